// Round 4
// baseline (199.822 us; speedup 1.0000x reference)
//
#include <hip/hip_runtime.h>

#define NTHREADS 1024
#define NC 64
#define NWAVES (NTHREADS / 64)

__device__ __forceinline__ float sigmoidf_(float x) {
    return 1.0f / (1.0f + expf(-x));
}

// grid = 4*B blocks of 1024 threads -> 2 blocks/CU (VGPR<=64, 32 waves/CU).
// Each block simulates the FULL row (cascade couples all D) but writes only
// its quarter. Siblings of a row differ by 128 in blockIdx (128%8==0) -> same
// XCD, so duplicate x reads hit that XCD's L2. Cluster counts exploit
// cluster(d) = d%64 with d = 4*tid + (n>>2)*4096 + (n&3) =>
// cluster = (4*lane + (n&3)) & 63: lanes l, l+16, l+32, l+48 share a cluster,
// so 2 shfl_xor + per-wave LDS partials replace atomics. W is transposed in
// LDS so the 64-thread matvec is conflict-free. Matvec keeps the exact serial
// fp32 accumulation order of the round-1 passing kernel (bitwise identical).
// NOTE: nontemporal stores REGRESSED here (WRITE_SIZE 65->219 MB, nt bypasses
// L2 write-combining) -> plain float4 stores through L2.
__global__ __launch_bounds__(NTHREADS, 8)   // 8 waves/EU -> 2 blocks/CU
void lif_persistent(const float* __restrict__ x,       // [T,B,D]
                    const float* __restrict__ th_raw,  // [D]
                    const float* __restrict__ bm_raw,  // [1]
                    const float* __restrict__ bs_raw,  // [1]
                    const float* __restrict__ nw,      // [NC,NC]
                    const float* __restrict__ gain,    // [NC]
                    const int*   __restrict__ cids,    // [D] (== d % 64)
                    float* __restrict__ out_s,         // [T,B,D]
                    float* __restrict__ out_v,         // [T,B,D]
                    int T, int B, int D, float inv_pc)
{
    __shared__ float sWT[NC * NC];        // sWT[c2*64 + c] = sigmoid(nw[c*64 + c2])
    __shared__ float sPart[NWAVES * NC];  // per-wave cluster partial counts
    __shared__ float sCf[NC];             // total counts (written/read by wave 0)
    __shared__ float sNs[NC];             // neighbor signal

    const int tid  = threadIdx.x;
    const int lane = tid & 63;
    const int wave = tid >> 6;
    const int bid  = blockIdx.x;
    const int b    = bid % B;         // row
    const int q    = bid / B;         // quarter 0..3 that this block stores
    const int h    = q >> 1;          // which n-group (0: d<D/2, 1: d>=D/2)
    const int Dh   = D >> 1;

    for (int i = tid; i < NC * NC; i += NTHREADS) {
        const int c2 = i >> 6, c = i & 63;
        sWT[i] = sigmoidf_(nw[c * NC + c2]);
    }
    float gc = 0.0f;
    if (wave == 0) gc = gain[lane];

    const float bm  = fminf(fmaxf(sigmoidf_(bm_raw[0]), 0.8f), 0.98f);
    const float omb = __fsub_rn(1.0f, bm);
    const float bs  = sigmoidf_(bs_raw[0]);

    float v[8], isyn[8], th[8], sv[8];
    int refr[8];
#pragma unroll
    for (int n = 0; n < 8; ++n) {
        const int d = 4 * tid + (n >> 2) * Dh + (n & 3);
        v[n] = 0.0f; isyn[n] = 0.0f; refr[n] = 0;
        th[n] = fminf(fmaxf(th_raw[d], 0.05f), 0.5f);
    }
    const bool writer = (tid >> 9) == (q & 1);   // this thread stores its group-h float4

    // prefetch t=0 x into registers
    size_t base = (size_t)b * D;
    float4 xc0 = *(const float4*)(x + base + 4 * tid);
    float4 xc1 = *(const float4*)(x + base + Dh + 4 * tid);
    __syncthreads();

    for (int t = 0; t < T; ++t) {
        // issue next step's x loads early: they overlap the whole step's
        // compute and are drained by the pre-barrier vmcnt anyway
        const size_t nbase = base + (size_t)B * D;
        float4 xn0, xn1;
        if (t + 1 < T) {
            xn0 = *(const float4*)(x + nbase + 4 * tid);
            xn1 = *(const float4*)(x + nbase + Dh + 4 * tid);
        }
        const float xv[8] = {xc0.x, xc0.y, xc0.z, xc0.w,
                             xc1.x, xc1.y, xc1.z, xc1.w};

#pragma unroll
        for (int n = 0; n < 8; ++n) {
            // exact numpy fp32 op order: no fma contraction
            isyn[n] = __fadd_rn(__fmul_rn(bs, isyn[n]), xv[n]);
            const float nv = __fadd_rn(__fmul_rn(bm, v[n]),
                                       __fmul_rn(omb, isyn[n]));
            const float vm = (refr[n] > 0) ? -0.1f : nv;
            sv[n] = (vm >= th[n]) ? 1.0f : 0.0f;
            v[n]  = vm;
        }

        if (writer) {   // spikes final: store early, overlap with reduction
            const int o = 4 * h;
            *(float4*)(out_s + base + h * Dh + 4 * tid) =
                make_float4(sv[o], sv[o+1], sv[o+2], sv[o+3]);
        }

        // per-thread cluster partials: components n and n+4 share cluster (4*lane+n)&63
        float c4[4];
#pragma unroll
        for (int k = 0; k < 4; ++k) {
            c4[k] = sv[k] + sv[k + 4];                       // exact small ints
            c4[k] += __shfl_xor(c4[k], 16, 64);
            c4[k] += __shfl_xor(c4[k], 32, 64);
        }
        if (lane < 16) {
            const float4 p = make_float4(c4[0], c4[1], c4[2], c4[3]);
            *(float4*)(sPart + wave * NC + 4 * lane) = p;    // cluster 4*lane+k
        }
        __syncthreads();   // (b) partials visible

        if (wave == 0) {
            float cf = sPart[lane];                          // exact int sums
#pragma unroll
            for (int w = 1; w < NWAVES; ++w)
                cf = __fadd_rn(cf, sPart[w * NC + lane]);
            sCf[lane] = cf;
            // same-wave LDS write->read: in-order, no barrier needed
            float acc = 0.0f;
#pragma unroll 8
            for (int c2 = 0; c2 < NC; ++c2)
                acc = __fadd_rn(acc,
                      __fmul_rn(__fmul_rn(sCf[c2], inv_pc), sWT[c2 * NC + lane]));
            sNs[lane] = __fmul_rn(acc, gc);
        }
        __syncthreads();   // (c) sNs ready

        const float myNs = sNs[lane];   // conflict-free; then redistribute by shfl
#pragma unroll
        for (int n = 0; n < 8; ++n) {
            const float ns = __shfl(myNs, (4 * lane + (n & 3)) & 63, 64);
            isyn[n] = __fadd_rn(isyn[n], ns);
            v[n]    = __fsub_rn(v[n], __fmul_rn(sv[n], th[n]));
            refr[n] = (sv[n] > 0.0f) ? 2 : max(refr[n] - 1, 0);
        }

        if (writer) {
            const int o = 4 * h;
            *(float4*)(out_v + base + h * Dh + 4 * tid) =
                make_float4(v[o], v[o+1], v[o+2], v[o+3]);
        }

        xc0 = xn0; xc1 = xn1; base = nbase;
    }
}

extern "C" void kernel_launch(void* const* d_in, const int* in_sizes, int n_in,
                              void* d_out, int out_size, void* d_ws, size_t ws_size,
                              hipStream_t stream) {
    const float* x    = (const float*)d_in[0];
    const float* th   = (const float*)d_in[1];
    const float* bm   = (const float*)d_in[2];
    const float* bs   = (const float*)d_in[3];
    const float* nw   = (const float*)d_in[4];
    const float* gain = (const float*)d_in[5];
    const int*   cids = (const int*)d_in[6];

    const int D  = in_sizes[1];          // 8192
    const int TB = in_sizes[0] / D;      // 1024
    const int T  = 8;
    const int B  = TB / T;               // 128

    float* out_s = (float*)d_out;
    float* out_v = out_s + (size_t)T * B * D;

    int per_cluster = D / NC; if (per_cluster < 1) per_cluster = 1;
    const float inv_pc = 1.0f / (float)per_cluster;

    dim3 grid(4 * B), block(NTHREADS);
    hipLaunchKernelGGL(lif_persistent, grid, block, 0, stream,
                       x, th, bm, bs, nw, gain, cids,
                       out_s, out_v, T, B, D, inv_pc);
}

// Round 5
// 112.933 us; speedup vs baseline: 1.7694x; 1.7694x over previous
//
#include <hip/hip_runtime.h>

#define NTHREADS 1024
#define NC 64
#define NWAVES (NTHREADS / 64)

__device__ __forceinline__ float sigmoidf_(float x) {
    return 1.0f / (1.0f + expf(-x));
}

// grid = 2*B blocks of 1024 threads, 1 block/CU, launch_bounds(1024,4) ->
// 128-VGPR budget. DO NOT force 8 waves/EU here: the 64-VGPR cap makes the
// compiler spill ~25 regs to scratch and HBM traffic explodes 84->467 MB
// (measured rounds 3/4: WRITE_SIZE 67->336 MB, VGPR_Count pinned at 32).
// Each block simulates the FULL row (cascade couples all D) and writes its
// half. Siblings (bid, bid+128) land on the same XCD (128%8==0) -> x reads
// shared in that XCD's L2. cluster(d)=d%64 and d=4*tid+(n>>2)*4096+(n&3) =>
// cluster=(4*lane+(n&3))&63: lanes l,l+16,l+32,l+48 share a cluster, so
// 2 shfl_xor + per-wave LDS partials replace atomics; W transposed in LDS so
// the wave-0 matvec is conflict-free and keeps the round-1 serial fp32 order.
// v is final BEFORE the cascade (reset-subtract is sNs-independent), so both
// output stores issue right after barrier (b) and overlap the matvec.
__global__ __launch_bounds__(NTHREADS, 4)
void lif_persistent(const float* __restrict__ x,       // [T,B,D]
                    const float* __restrict__ th_raw,  // [D]
                    const float* __restrict__ bm_raw,  // [1]
                    const float* __restrict__ bs_raw,  // [1]
                    const float* __restrict__ nw,      // [NC,NC]
                    const float* __restrict__ gain,    // [NC]
                    const int*   __restrict__ cids,    // [D] (== d % 64)
                    float* __restrict__ out_s,         // [T,B,D]
                    float* __restrict__ out_v,         // [T,B,D]
                    int T, int B, int D, float inv_pc)
{
    __shared__ float sWT[NC * NC];        // sWT[c2*64 + c] = sigmoid(nw[c*64 + c2])
    __shared__ float sPart[NWAVES * NC];  // per-wave cluster partial counts
    __shared__ float sCf[NC];             // totals (written/read by wave 0)
    __shared__ float sNs[NC];             // neighbor signal

    const int tid  = threadIdx.x;
    const int lane = tid & 63;
    const int wave = tid >> 6;
    const int bid  = blockIdx.x;
    const int b    = bid % B;         // row
    const int half = bid / B;         // which half of the row this block stores
    const int Dh   = D >> 1;

    for (int i = tid; i < NC * NC; i += NTHREADS) {
        const int c2 = i >> 6, c = i & 63;
        sWT[i] = sigmoidf_(nw[c * NC + c2]);
    }
    float gc = 0.0f;
    if (wave == 0) gc = gain[lane];

    const float bm  = fminf(fmaxf(sigmoidf_(bm_raw[0]), 0.8f), 0.98f);
    const float omb = __fsub_rn(1.0f, bm);
    const float bs  = sigmoidf_(bs_raw[0]);

    float v[8], isyn[8], th[8], sv[8];
    int refr[8];
#pragma unroll
    for (int n = 0; n < 8; ++n) {
        const int d = 4 * tid + (n >> 2) * Dh + (n & 3);
        v[n] = 0.0f; isyn[n] = 0.0f; refr[n] = 0;
        th[n] = fminf(fmaxf(th_raw[d], 0.05f), 0.5f);
    }

    // prefetch t=0 x into registers
    size_t base = (size_t)b * D;
    float4 xc0 = *(const float4*)(x + base + 4 * tid);
    float4 xc1 = *(const float4*)(x + base + Dh + 4 * tid);
    __syncthreads();

    for (int t = 0; t < T; ++t) {
        const size_t nbase = base + (size_t)B * D;
        float4 xn0, xn1;
        if (t + 1 < T) {   // issue next step's loads early; latency hidden by compute
            xn0 = *(const float4*)(x + nbase + 4 * tid);
            xn1 = *(const float4*)(x + nbase + Dh + 4 * tid);
        }
        const float xv[8] = {xc0.x, xc0.y, xc0.z, xc0.w,
                             xc1.x, xc1.y, xc1.z, xc1.w};

#pragma unroll
        for (int n = 0; n < 8; ++n) {
            // exact numpy fp32 op order: no fma contraction
            isyn[n] = __fadd_rn(__fmul_rn(bs, isyn[n]), xv[n]);
            const float nv = __fadd_rn(__fmul_rn(bm, v[n]),
                                       __fmul_rn(omb, isyn[n]));
            const float vm = (refr[n] > 0) ? -0.1f : nv;
            const float s  = (vm >= th[n]) ? 1.0f : 0.0f;
            sv[n] = s;
            v[n]  = __fsub_rn(vm, __fmul_rn(s, th[n]));   // final: output value
        }

        // per-thread cluster partials: n and n+4 share cluster (4*lane+(n&3))&63
        float c4[4];
#pragma unroll
        for (int k = 0; k < 4; ++k) {
            c4[k] = sv[k] + sv[k + 4];                    // exact small ints
            c4[k] += __shfl_xor(c4[k], 16, 64);
            c4[k] += __shfl_xor(c4[k], 32, 64);
        }
        if (lane < 16) {
            const float4 p = make_float4(c4[0], c4[1], c4[2], c4[3]);
            *(float4*)(sPart + wave * NC + 4 * lane) = p; // cluster 4*lane+k
        }
        __syncthreads();   // (b) partials visible

        // both outputs are final -> store now, overlapping the wave-0 matvec;
        // the stores drain at barrier (c)
        {
            const int o = 4 * half;
            *(float4*)(out_s + base + half * Dh + 4 * tid) =
                make_float4(sv[o], sv[o+1], sv[o+2], sv[o+3]);
            *(float4*)(out_v + base + half * Dh + 4 * tid) =
                make_float4(v[o], v[o+1], v[o+2], v[o+3]);
        }

        if (wave == 0) {
            float cf = sPart[lane];                       // exact int sums
#pragma unroll
            for (int w = 1; w < NWAVES; ++w)
                cf = __fadd_rn(cf, sPart[w * NC + lane]);
            sCf[lane] = cf;
            // same-wave LDS write->read: in-order, no barrier needed
            float acc = 0.0f;
#pragma unroll 8
            for (int c2 = 0; c2 < NC; ++c2)
                acc = __fadd_rn(acc,
                      __fmul_rn(__fmul_rn(sCf[c2], inv_pc), sWT[c2 * NC + lane]));
            sNs[lane] = __fmul_rn(acc, gc);
        }
        __syncthreads();   // (c) sNs ready

        const float myNs = sNs[lane];   // conflict-free; redistribute by shfl
#pragma unroll
        for (int n = 0; n < 8; ++n) {
            const float ns = __shfl(myNs, (4 * lane + (n & 3)) & 63, 64);
            isyn[n] = __fadd_rn(isyn[n], ns);
            refr[n] = (sv[n] > 0.0f) ? 2 : max(refr[n] - 1, 0);
        }

        xc0 = xn0; xc1 = xn1; base = nbase;
    }
}

extern "C" void kernel_launch(void* const* d_in, const int* in_sizes, int n_in,
                              void* d_out, int out_size, void* d_ws, size_t ws_size,
                              hipStream_t stream) {
    const float* x    = (const float*)d_in[0];
    const float* th   = (const float*)d_in[1];
    const float* bm   = (const float*)d_in[2];
    const float* bs   = (const float*)d_in[3];
    const float* nw   = (const float*)d_in[4];
    const float* gain = (const float*)d_in[5];
    const int*   cids = (const int*)d_in[6];

    const int D  = in_sizes[1];          // 8192
    const int TB = in_sizes[0] / D;      // 1024
    const int T  = 8;
    const int B  = TB / T;               // 128

    float* out_s = (float*)d_out;
    float* out_v = out_s + (size_t)T * B * D;

    int per_cluster = D / NC; if (per_cluster < 1) per_cluster = 1;
    const float inv_pc = 1.0f / (float)per_cluster;

    dim3 grid(2 * B), block(NTHREADS);
    hipLaunchKernelGGL(lif_persistent, grid, block, 0, stream,
                       x, th, bm, bs, nw, gain, cids,
                       out_s, out_v, T, B, D, inv_pc);
}

// Round 6
// 108.112 us; speedup vs baseline: 1.8483x; 1.0446x over previous
//
#include <hip/hip_runtime.h>

#define NTHREADS 1024
#define NC 64
#define NWAVES (NTHREADS / 64)

__device__ __forceinline__ float sigmoidf_(float x) {
    return 1.0f / (1.0f + expf(-x));
}

// grid = 2*B blocks of 1024 threads, 1 block/CU, launch_bounds(1024,4) ->
// 128-VGPR budget. DO NOT force 8 waves/EU: the 64-VGPR cap spills ~25 regs
// to scratch and HBM traffic explodes 84->467 MB (measured rounds 3/4).
// Each block simulates the FULL row (cascade couples all D) and writes its
// half. Siblings (bid, bid+128) land on the same XCD (128%8==0) -> x reads
// shared in that XCD's L2. cluster(d)=d%64 and d=4*tid+(n>>2)*4096+(n&3) =>
// cluster=(4*lane+(n&3))&63: lanes l,l+16,l+32,l+48 share a cluster, so
// 2 shfl_xor + per-wave LDS partials replace atomics; W transposed in LDS so
// the wave-0 matvec is conflict-free and keeps the round-1 serial fp32 order.
// STORES are issued AFTER barrier (c): __syncthreads drains vmcnt(0), so a
// store issued between (b) and (c) serializes its completion into the step's
// critical path; issued after (c) it drains at the NEXT step's (b), fully
// overlapped with the next compute phase.
__global__ __launch_bounds__(NTHREADS, 4)
void lif_persistent(const float* __restrict__ x,       // [T,B,D]
                    const float* __restrict__ th_raw,  // [D]
                    const float* __restrict__ bm_raw,  // [1]
                    const float* __restrict__ bs_raw,  // [1]
                    const float* __restrict__ nw,      // [NC,NC]
                    const float* __restrict__ gain,    // [NC]
                    const int*   __restrict__ cids,    // [D] (== d % 64)
                    float* __restrict__ out_s,         // [T,B,D]
                    float* __restrict__ out_v,         // [T,B,D]
                    int T, int B, int D, float inv_pc)
{
    __shared__ float sWT[NC * NC];        // sWT[c2*64 + c] = sigmoid(nw[c*64 + c2])
    __shared__ float sPart[NWAVES * NC];  // per-wave cluster partial counts
    __shared__ float sCf[NC];             // totals (written/read by wave 0)
    __shared__ float sNs[NC];             // neighbor signal

    const int tid  = threadIdx.x;
    const int lane = tid & 63;
    const int wave = tid >> 6;
    const int bid  = blockIdx.x;
    const int b    = bid % B;         // row
    const int half = bid / B;         // which half of the row this block stores
    const int Dh   = D >> 1;

    for (int i = tid; i < NC * NC; i += NTHREADS) {
        const int c2 = i >> 6, c = i & 63;
        sWT[i] = sigmoidf_(nw[c * NC + c2]);
    }
    float gc = 0.0f;
    if (wave == 0) gc = gain[lane];

    const float bm  = fminf(fmaxf(sigmoidf_(bm_raw[0]), 0.8f), 0.98f);
    const float omb = __fsub_rn(1.0f, bm);
    const float bs  = sigmoidf_(bs_raw[0]);

    float v[8], isyn[8], th[8], sv[8];
    int refr[8];
#pragma unroll
    for (int n = 0; n < 8; ++n) {
        const int d = 4 * tid + (n >> 2) * Dh + (n & 3);
        v[n] = 0.0f; isyn[n] = 0.0f; refr[n] = 0;
        th[n] = fminf(fmaxf(th_raw[d], 0.05f), 0.5f);
    }

    // prefetch t=0 x into registers
    size_t base = (size_t)b * D;
    float4 xc0 = *(const float4*)(x + base + 4 * tid);
    float4 xc1 = *(const float4*)(x + base + Dh + 4 * tid);
    __syncthreads();

    for (int t = 0; t < T; ++t) {
        // next step's loads, issued early; address clamped on the last step so
        // the loads stay unconditional (in-bounds, result unused)
        const size_t nbase = (t + 1 < T) ? base + (size_t)B * D : base;
        float4 xn0 = *(const float4*)(x + nbase + 4 * tid);
        float4 xn1 = *(const float4*)(x + nbase + Dh + 4 * tid);

        const float xv[8] = {xc0.x, xc0.y, xc0.z, xc0.w,
                             xc1.x, xc1.y, xc1.z, xc1.w};

#pragma unroll
        for (int n = 0; n < 8; ++n) {
            // exact numpy fp32 op order: no fma contraction
            isyn[n] = __fadd_rn(__fmul_rn(bs, isyn[n]), xv[n]);
            const float nv = __fadd_rn(__fmul_rn(bm, v[n]),
                                       __fmul_rn(omb, isyn[n]));
            const float vm = (refr[n] > 0) ? -0.1f : nv;
            const float s  = (vm >= th[n]) ? 1.0f : 0.0f;
            sv[n] = s;
            v[n]  = __fsub_rn(vm, __fmul_rn(s, th[n]));   // final: output value
        }

        // per-thread cluster partials: n and n+4 share cluster (4*lane+(n&3))&63
        float c4[4];
#pragma unroll
        for (int k = 0; k < 4; ++k) {
            c4[k] = sv[k] + sv[k + 4];                    // exact small ints
            c4[k] += __shfl_xor(c4[k], 16, 64);
            c4[k] += __shfl_xor(c4[k], 32, 64);
        }
        if (lane < 16) {
            const float4 p = make_float4(c4[0], c4[1], c4[2], c4[3]);
            *(float4*)(sPart + wave * NC + 4 * lane) = p; // cluster 4*lane+k
        }
        __syncthreads();   // (b) partials visible; prev-step stores drain here

        if (wave == 0) {
            float cf = sPart[lane];                       // exact int sums
#pragma unroll
            for (int w = 1; w < NWAVES; ++w)
                cf = __fadd_rn(cf, sPart[w * NC + lane]);
            sCf[lane] = cf;
            // same-wave LDS write->read: in-order, no barrier needed
            float acc = 0.0f;
#pragma unroll 8
            for (int c2 = 0; c2 < NC; ++c2)
                acc = __fadd_rn(acc,
                      __fmul_rn(__fmul_rn(sCf[c2], inv_pc), sWT[c2 * NC + lane]));
            sNs[lane] = __fmul_rn(acc, gc);
        }
        __syncthreads();   // (c) sNs ready

        // stores issued after (c): drain overlapped with next step's compute
        {
            const int o = 4 * half;
            *(float4*)(out_s + base + half * Dh + 4 * tid) =
                make_float4(sv[o], sv[o+1], sv[o+2], sv[o+3]);
            *(float4*)(out_v + base + half * Dh + 4 * tid) =
                make_float4(v[o], v[o+1], v[o+2], v[o+3]);
        }

        const float myNs = sNs[lane];   // conflict-free; redistribute by shfl
#pragma unroll
        for (int n = 0; n < 8; ++n) {
            const float ns = __shfl(myNs, (4 * lane + (n & 3)) & 63, 64);
            isyn[n] = __fadd_rn(isyn[n], ns);
            refr[n] = (sv[n] > 0.0f) ? 2 : max(refr[n] - 1, 0);
        }

        xc0 = xn0; xc1 = xn1; base += (size_t)B * D;
    }
}

extern "C" void kernel_launch(void* const* d_in, const int* in_sizes, int n_in,
                              void* d_out, int out_size, void* d_ws, size_t ws_size,
                              hipStream_t stream) {
    const float* x    = (const float*)d_in[0];
    const float* th   = (const float*)d_in[1];
    const float* bm   = (const float*)d_in[2];
    const float* bs   = (const float*)d_in[3];
    const float* nw   = (const float*)d_in[4];
    const float* gain = (const float*)d_in[5];
    const int*   cids = (const int*)d_in[6];

    const int D  = in_sizes[1];          // 8192
    const int TB = in_sizes[0] / D;      // 1024
    const int T  = 8;
    const int B  = TB / T;               // 128

    float* out_s = (float*)d_out;
    float* out_v = out_s + (size_t)T * B * D;

    int per_cluster = D / NC; if (per_cluster < 1) per_cluster = 1;
    const float inv_pc = 1.0f / (float)per_cluster;

    dim3 grid(2 * B), block(NTHREADS);
    hipLaunchKernelGGL(lif_persistent, grid, block, 0, stream,
                       x, th, bm, bs, nw, gain, cids,
                       out_s, out_v, T, B, D, inv_pc);
}